// Round 2
// baseline (277.281 us; speedup 1.0000x reference)
//
#include <hip/hip_runtime.h>
#include <hip/hip_bf16.h>

#define TPB 256
#define SH 6
#define BW 64  // nodes per bucket = 1<<SH; NBUK must be <= 1024 (N <= 65536)

typedef unsigned short u16;
typedef __attribute__((ext_vector_type(8))) __bf16 bf16x8;  // MFMA A/B frag (4 VGPRs)
typedef __attribute__((ext_vector_type(4))) float f32x4;    // MFMA C/D frag
typedef __attribute__((ext_vector_type(8))) unsigned short ushort8v;  // 16B gather unit

// bf16 helpers: payload stored as bf16 (halves gather BW), accumulate in fp32.
__device__ __forceinline__ u16 f_to_bf(float f) {
    unsigned u = __float_as_uint(f);
    return (u16)((u + 0x7fff + ((u >> 16) & 1)) >> 16);  // RNE
}
__device__ __forceinline__ float4 bf4_to_f4(ushort4 v) {
    float4 r;
    r.x = __uint_as_float((unsigned)v.x << 16);
    r.y = __uint_as_float((unsigned)v.y << 16);
    r.z = __uint_as_float((unsigned)v.z << 16);
    r.w = __uint_as_float((unsigned)v.w << 16);
    return r;
}
__device__ __forceinline__ void facc(float4& a, float4 v) {
    a.x += v.x; a.y += v.y; a.z += v.z; a.w += v.w;
}

// ---- float8 (2x float4) payload ops: 16B/lane gather granularity ----
struct f8v { float4 a, b; };
__device__ __forceinline__ f8v f8zero() {
    f8v r;
    r.a = make_float4(0.f, 0.f, 0.f, 0.f);
    r.b = r.a;
    return r;
}
__device__ __forceinline__ f8v bf8_to_f8(ushort8v v) {
    f8v r;
    r.a.x = __uint_as_float((unsigned)v[0] << 16);
    r.a.y = __uint_as_float((unsigned)v[1] << 16);
    r.a.z = __uint_as_float((unsigned)v[2] << 16);
    r.a.w = __uint_as_float((unsigned)v[3] << 16);
    r.b.x = __uint_as_float((unsigned)v[4] << 16);
    r.b.y = __uint_as_float((unsigned)v[5] << 16);
    r.b.z = __uint_as_float((unsigned)v[6] << 16);
    r.b.w = __uint_as_float((unsigned)v[7] << 16);
    return r;
}
__device__ __forceinline__ void facc8(f8v& x, f8v v) {
    facc(x.a, v.a);
    facc(x.b, v.b);
}
__device__ __forceinline__ f8v shfl_xor8(f8v v, int mask, int width) {
    v.a.x = __shfl_xor(v.a.x, mask, width);
    v.a.y = __shfl_xor(v.a.y, mask, width);
    v.a.z = __shfl_xor(v.a.z, mask, width);
    v.a.w = __shfl_xor(v.a.w, mask, width);
    v.b.x = __shfl_xor(v.b.x, mask, width);
    v.b.y = __shfl_xor(v.b.y, mask, width);
    v.b.z = __shfl_xor(v.b.z, mask, width);
    v.b.w = __shfl_xor(v.b.w, mask, width);
    return v;
}

// Software-pipelined 16B/lane gather: per edge, lane loads ushort8 (8 bf16 ch).
// Halves per-edge instruction overhead (addr math, load count, redundant col[]
// loads) vs the 8B version and doubles bytes-in-flight at the same depth.
template <int C>
__device__ __forceinline__ f8v gather_sum8(const u16* __restrict__ HW,
                                           const int* __restrict__ col,
                                           int c0, int ps, int pe) {
    f8v A0 = f8zero(), A1 = f8zero(), A2 = f8zero(), A3 = f8zero();
    int p = ps;
    for (; p + 8 <= pe; p += 8) {
        int j[8];
        ushort8v d[8];
#pragma unroll
        for (int k = 0; k < 8; k++) j[k] = col[p + k];
#pragma unroll
        for (int k = 0; k < 8; k++) d[k] = *(const ushort8v*)&HW[(size_t)j[k] * C + c0];
        facc8(A0, bf8_to_f8(d[0])); facc8(A1, bf8_to_f8(d[1]));
        facc8(A2, bf8_to_f8(d[2])); facc8(A3, bf8_to_f8(d[3]));
        facc8(A0, bf8_to_f8(d[4])); facc8(A1, bf8_to_f8(d[5]));
        facc8(A2, bf8_to_f8(d[6])); facc8(A3, bf8_to_f8(d[7]));
    }
    if (p + 4 <= pe) {
        int j[4];
        ushort8v d[4];
#pragma unroll
        for (int k = 0; k < 4; k++) j[k] = col[p + k];
#pragma unroll
        for (int k = 0; k < 4; k++) d[k] = *(const ushort8v*)&HW[(size_t)j[k] * C + c0];
        facc8(A0, bf8_to_f8(d[0])); facc8(A1, bf8_to_f8(d[1]));
        facc8(A2, bf8_to_f8(d[2])); facc8(A3, bf8_to_f8(d[3]));
        p += 4;
    }
    if (p + 2 <= pe) {
        int j0 = col[p], j1 = col[p + 1];
        ushort8v d0 = *(const ushort8v*)&HW[(size_t)j0 * C + c0];
        ushort8v d1 = *(const ushort8v*)&HW[(size_t)j1 * C + c0];
        facc8(A0, bf8_to_f8(d0));
        facc8(A1, bf8_to_f8(d1));
        p += 2;
    }
    if (p < pe) {
        int j = col[p];
        facc8(A0, bf8_to_f8(*(const ushort8v*)&HW[(size_t)j * C + c0]));
    }
    facc8(A0, A1); facc8(A2, A3); facc8(A0, A2);
    return A0;
}

// ---------------- capacity-bucket CSR build (no count/scan passes) ----------------
// Bucket b owns region [b*cap, (b+1)*cap) of ebuf/col. bcur is zero-initialized;
// scatter reserves runs per block via one atomicAdd per touched bucket.

__global__ void bucket_scatter_kernel(const int* __restrict__ e0, const int* __restrict__ e1,
                                      int E, int* __restrict__ bcur,
                                      int* __restrict__ ebuf0, int* __restrict__ ebuf1,
                                      int nbuk, int cap) {
    int g = blockIdx.y;
    const int* src = g ? e1 : e0;
    const int* dst = src + E;
    int* ebuf = g ? ebuf1 : ebuf0;
    int* bu = bcur + g * 1024;
    __shared__ int hist[1024];
    for (int t = threadIdx.x; t < 1024; t += TPB) hist[t] = 0;
    __syncthreads();
    int base = blockIdx.x * 4096;
    int pk[16], bk[16], rk[16];
#pragma unroll
    for (int k = 0; k < 16; k++) {
        int e = base + k * TPB + (int)threadIdx.x;
        bk[k] = -1;
        if (e < E) {
            int s = src[e], d = dst[e];
            int b = d >> SH;
            bk[k] = b;
            pk[k] = (s << SH) | (d & (BW - 1));
            rk[k] = atomicAdd(&hist[b], 1);
        }
    }
    __syncthreads();
    for (int t = threadIdx.x; t < nbuk; t += TPB) {
        int h = hist[t];
        hist[t] = h ? atomicAdd(&bu[t], h) : 0;
    }
    __syncthreads();
#pragma unroll
    for (int k = 0; k < 16; k++)
        if (bk[k] >= 0) {
            int pos = hist[bk[k]] + rk[k];
            if (pos < cap) ebuf[(size_t)bk[k] * cap + pos] = pk[k];
        }
}

// Per-bucket: histogram -> local scan -> soff/eoff/dinv -> fill col (bucket-local).
__global__ void bucket_csr_kernel(const int* __restrict__ ebuf0, const int* __restrict__ ebuf1,
                                  const int* __restrict__ bcur, int n, int cap,
                                  int* __restrict__ soff0, int* __restrict__ soff1,
                                  int* __restrict__ eoff0, int* __restrict__ eoff1,
                                  float* __restrict__ dinv0, float* __restrict__ dinv1,
                                  int* __restrict__ col0, int* __restrict__ col1) {
    int g = blockIdx.y;
    int b = blockIdx.x;
    const int* ebuf = g ? ebuf1 : ebuf0;
    int* soff = g ? soff1 : soff0;
    int* eoff = g ? eoff1 : eoff0;
    float* dinv = g ? dinv1 : dinv0;
    int* col = g ? col1 : col0;
    __shared__ int h[BW], nb[BW], nrank[BW];
    int tid = threadIdx.x;
    if (tid < BW) h[tid] = 0;
    __syncthreads();
    int s = b * cap;
    int cnt = min(bcur[g * 1024 + b], cap);
    int e = s + cnt;
    for (int i = s + tid; i < e; i += TPB)
        atomicAdd(&h[ebuf[i] & (BW - 1)], 1);
    __syncthreads();
    if (tid < BW) {
        int v = h[tid];
        int x = v;
        for (int d = 1; d < BW; d <<= 1) {
            int u = __shfl_up(x, d, 64);
            if (tid >= d) x += u;
        }
        int base = s + x - v;  // exclusive prefix within bucket region
        nb[tid] = base;
        nrank[tid] = 0;
        int node = b * BW + tid;
        if (node < n) {
            soff[node] = base;
            eoff[node] = base + v;
            dinv[node] = rsqrtf((float)v + 1.0f);
        }
    }
    __syncthreads();
    for (int i = s + tid; i < e; i += TPB) {
        int p = ebuf[i];
        int lo = p & (BW - 1);
        int r = atomicAdd(&nrank[lo], 1);
        col[nb[lo] + r] = p >> SH;
    }
}

// ---------------- dense matmul via MFMA: Y = bf16( dinv[n] * (X @ W) ) ----------

template <int CIN, int COUT>
__global__ void matmul_kernel(const float* __restrict__ X0, const float* __restrict__ X1,
                              const float* __restrict__ W,
                              const float* __restrict__ dinv0, const float* __restrict__ dinv1,
                              u16* __restrict__ Y0, u16* __restrict__ Y1, int n) {
    constexpr int CINP = CIN + 8;
    constexpr int NT = COUT / 16;
    constexpr int KT = CIN / 32;
    __shared__ u16 Xs[64 * CINP];
    __shared__ u16 Wt[COUT * CINP];

    int g = blockIdx.y;
    const float* X = g ? X1 : X0;
    const float* dinv = g ? dinv1 : dinv0;
    u16* Y = g ? Y1 : Y0;
    int nb0 = blockIdx.x * 64;

    for (int i = threadIdx.x; i < 64 * (CIN / 4); i += TPB) {
        int nn = i / (CIN / 4), kc = i % (CIN / 4);
        float4 v = make_float4(0.f, 0.f, 0.f, 0.f);
        if (nb0 + nn < n) v = *(const float4*)&X[(size_t)(nb0 + nn) * CIN + 4 * kc];
        ushort4 b;
        b.x = f_to_bf(v.x); b.y = f_to_bf(v.y); b.z = f_to_bf(v.z); b.w = f_to_bf(v.w);
        *(ushort4*)&Xs[nn * CINP + 4 * kc] = b;
    }
    for (int i = threadIdx.x; i < CIN * (COUT / 4); i += TPB) {
        int k = i / (COUT / 4), nc4 = i % (COUT / 4);
        float4 v = *(const float4*)&W[(size_t)k * COUT + 4 * nc4];
        Wt[(4 * nc4 + 0) * CINP + k] = f_to_bf(v.x);
        Wt[(4 * nc4 + 1) * CINP + k] = f_to_bf(v.y);
        Wt[(4 * nc4 + 2) * CINP + k] = f_to_bf(v.z);
        Wt[(4 * nc4 + 3) * CINP + k] = f_to_bf(v.w);
    }
    __syncthreads();

    int lane = threadIdx.x & 63;
    int w = threadIdx.x >> 6;
    int m = lane & 15;
    int quad = lane >> 4;

    f32x4 acc[NT];
#pragma unroll
    for (int t = 0; t < NT; t++) acc[t] = (f32x4){0.f, 0.f, 0.f, 0.f};
#pragma unroll
    for (int kt = 0; kt < KT; kt++) {
        int k0 = kt * 32 + quad * 8;
        bf16x8 a = *(const bf16x8*)&Xs[(w * 16 + m) * CINP + k0];
#pragma unroll
        for (int t = 0; t < NT; t++) {
            bf16x8 b = *(const bf16x8*)&Wt[(t * 16 + m) * CINP + k0];
            acc[t] = __builtin_amdgcn_mfma_f32_16x16x32_bf16(a, b, acc[t], 0, 0, 0);
        }
    }
#pragma unroll
    for (int r = 0; r < 4; r++) {
        int node = nb0 + w * 16 + quad * 4 + r;
        if (node < n) {
            float d = dinv[node];
#pragma unroll
            for (int t = 0; t < NT; t++)
                Y[(size_t)node * COUT + t * 16 + m] = f_to_bf(acc[t][r] * d);
        }
    }
}

// ------- fused GCN agg (C channels, bf16 payload) + next-layer matmul epilogue -------
// Block = 16 nodes (TPN=16 threads/node). Each lane gathers 16B (8 channels) per
// edge; SPLIT = 16/(C/8) edge-list slices per node. Gather+relu produces H rows in
// LDS; then the same block computes Y = bf16(dinv * (H @ W2)) [COUT2 channels].

template <int C, int COUT2>
__global__ __launch_bounds__(TPB, 2)
void agg_mm_kernel(const u16* __restrict__ HW0, const u16* __restrict__ HW1,
                   const int* __restrict__ soff0, const int* __restrict__ soff1,
                   const int* __restrict__ eoff0, const int* __restrict__ eoff1,
                   const int* __restrict__ col0, const int* __restrict__ col1,
                   const float* __restrict__ dinv0, const float* __restrict__ dinv1,
                   const float* __restrict__ bias, const float* __restrict__ W2,
                   u16* __restrict__ Y0, u16* __restrict__ Y1, int n) {
    constexpr int CH8 = C / 8;             // lanes covering one row (16B each)
    constexpr int TPN = 16;                // threads per node
    constexpr int SPLIT = TPN / CH8;       // edge-list slices per node
    constexpr int HS = C + 4;              // padded H row stride (floats)
    constexpr int OPT = 16 * COUT2 / TPB;  // outputs per thread (2 or 1)
    __shared__ float Ws2[C * COUT2];
    __shared__ float Hs[16 * HS];

    int g = blockIdx.y;
    const u16* HW = g ? HW1 : HW0;
    const int* soff = g ? soff1 : soff0;
    const int* eoff = g ? eoff1 : eoff0;
    const int* col = g ? col1 : col0;
    const float* dinv = g ? dinv1 : dinv0;
    u16* Y = g ? Y1 : Y0;

    // stage W2 (fp32) while gather loads are in flight
    for (int i = threadIdx.x; i < C * COUT2 / 4; i += TPB)
        ((float4*)Ws2)[i] = ((const float4*)W2)[i];

    int tid = blockIdx.x * TPB + (int)threadIdx.x;
    int node = tid / TPN;
    int nl = threadIdx.x / TPN;
    int part = threadIdx.x % TPN;
    int sp = part / CH8;
    int c0 = (part % CH8) * 8;
    f8v o = f8zero();
    if (node < n) {
        int s = soff[node], e = eoff[node];
        int len = e - s;
        int chunk = (len + SPLIT - 1) / SPLIT;
        int ps = s + sp * chunk;
        int pe = min(ps + chunk, e);
        f8v r = gather_sum8<C>(HW, col, c0, ps, pe);
#pragma unroll
        for (int m = CH8; m < TPN; m <<= 1) facc8(r, shfl_xor8(r, m, TPN));
        if (sp == 0) {
            float di = dinv[node];
            f8v self = bf8_to_f8(*(const ushort8v*)&HW[(size_t)node * C + c0]);
            float4 b0 = *(const float4*)&bias[c0];
            float4 b1 = *(const float4*)&bias[c0 + 4];
            o.a.x = fmaxf(di * (r.a.x + self.a.x) + b0.x, 0.f);
            o.a.y = fmaxf(di * (r.a.y + self.a.y) + b0.y, 0.f);
            o.a.z = fmaxf(di * (r.a.z + self.a.z) + b0.z, 0.f);
            o.a.w = fmaxf(di * (r.a.w + self.a.w) + b0.w, 0.f);
            o.b.x = fmaxf(di * (r.b.x + self.b.x) + b1.x, 0.f);
            o.b.y = fmaxf(di * (r.b.y + self.b.y) + b1.y, 0.f);
            o.b.z = fmaxf(di * (r.b.z + self.b.z) + b1.z, 0.f);
            o.b.w = fmaxf(di * (r.b.w + self.b.w) + b1.w, 0.f);
        }
    }
    if (sp == 0) {
        *(float4*)&Hs[nl * HS + c0] = o.a;      // zeros for tail nodes
        *(float4*)&Hs[nl * HS + c0 + 4] = o.b;
    }
    __syncthreads();

    // matmul epilogue: node nl2, output channels p2*OPT..+OPT-1
    int nl2 = threadIdx.x >> 4;
    int p2 = threadIdx.x & 15;
    int onode = blockIdx.x * 16 + nl2;
    if (onode < n) {
        float d = dinv[onode];
        float acc[OPT];
#pragma unroll
        for (int j = 0; j < OPT; j++) acc[j] = 0.f;
#pragma unroll
        for (int k = 0; k < C; k++) {
            float h = Hs[nl2 * HS + k];
#pragma unroll
            for (int j = 0; j < OPT; j++)
                acc[j] += h * Ws2[k * COUT2 + p2 * OPT + j];
        }
        if constexpr (OPT == 2) {
            unsigned pack = (unsigned)f_to_bf(acc[0] * d) | ((unsigned)f_to_bf(acc[1] * d) << 16);
            *(unsigned*)&Y[(size_t)onode * COUT2 + p2 * 2] = pack;
        } else {
            Y[(size_t)onode * COUT2 + p2] = f_to_bf(acc[0] * d);
        }
    }
}

// Layer-3 aggregation (C=16: 2 lanes x 16B per row, SPLIT=8) + per-block colsum
// partials (NO atomics).
__global__ __launch_bounds__(TPB, 2)
void agg16_kernel(const u16* __restrict__ HW0, const u16* __restrict__ HW1,
                  const int* __restrict__ soff0, const int* __restrict__ soff1,
                  const int* __restrict__ eoff0, const int* __restrict__ eoff1,
                  const int* __restrict__ col0, const int* __restrict__ col1,
                  const float* __restrict__ dinv0, const float* __restrict__ dinv1,
                  const float* __restrict__ bias,
                  float* __restrict__ out0, float* __restrict__ out1,
                  float* __restrict__ pcol, int n) {
    int g = blockIdx.y;
    const u16* HW = g ? HW1 : HW0;
    const int* soff = g ? soff1 : soff0;
    const int* eoff = g ? eoff1 : eoff0;
    const int* col = g ? col1 : col0;
    const float* dinv = g ? dinv1 : dinv0;
    float* outp = g ? out1 : out0;
    int tid = blockIdx.x * blockDim.x + threadIdx.x;
    int node = tid / 16;
    int part = tid % 16;
    int sp = part / 2;           // 8 edge-list slices
    int c0 = (part % 2) * 8;     // 2 lanes cover 16 channels
    f8v o = f8zero();
    if (node < n) {
        int s = soff[node], e = eoff[node];
        int len = e - s;
        int chunk = (len + 7) / 8;
        int ps = s + sp * chunk;
        int pe = min(ps + chunk, e);
        f8v r = gather_sum8<16>(HW, col, c0, ps, pe);
#pragma unroll
        for (int m = 2; m < 16; m <<= 1) facc8(r, shfl_xor8(r, m, 16));
        if (sp == 0) {
            float di = dinv[node];
            f8v self = bf8_to_f8(*(const ushort8v*)&HW[(size_t)node * 16 + c0]);
            float4 b0 = *(const float4*)&bias[c0];
            float4 b1 = *(const float4*)&bias[c0 + 4];
            o.a.x = di * (r.a.x + self.a.x) + b0.x;
            o.a.y = di * (r.a.y + self.a.y) + b0.y;
            o.a.z = di * (r.a.z + self.a.z) + b0.z;
            o.a.w = di * (r.a.w + self.a.w) + b0.w;
            o.b.x = di * (r.b.x + self.b.x) + b1.x;
            o.b.y = di * (r.b.y + self.b.y) + b1.y;
            o.b.z = di * (r.b.z + self.b.z) + b1.z;
            o.b.w = di * (r.b.w + self.b.w) + b1.w;
            *(float4*)&outp[(size_t)node * 16 + c0] = o.a;
            *(float4*)&outp[(size_t)node * 16 + c0 + 4] = o.b;
        }
    }
    // per-block colsum partial (only sp==0 lanes hold data; parts 0,1 cover 16 ch)
    __shared__ f8v sd[TPB];
    sd[threadIdx.x] = (node < n && sp == 0) ? o : f8zero();
    __syncthreads();
    if (threadIdx.x < 64) {
        f8v a = sd[threadIdx.x];
        facc8(a, sd[threadIdx.x + 64]);
        facc8(a, sd[threadIdx.x + 128]);
        facc8(a, sd[threadIdx.x + 192]);
        sd[threadIdx.x] = a;
    }
    __syncthreads();
    if (threadIdx.x < 16) {
        f8v a = sd[threadIdx.x];
        facc8(a, sd[threadIdx.x + 16]);
        facc8(a, sd[threadIdx.x + 32]);
        facc8(a, sd[threadIdx.x + 48]);
        sd[threadIdx.x] = a;
    }
    __syncthreads();
    if (threadIdx.x < 2) {
        f8v a = sd[threadIdx.x];
        float* dst = &pcol[((size_t)g * gridDim.x + blockIdx.x) * 16 + threadIdx.x * 8];
        *(float4*)&dst[0] = a.a;
        *(float4*)&dst[4] = a.b;
    }
}

// ---------------- cvec: coalesced reduce of pcol partials + tanh(mean @ Wa) ----------

__global__ void cvec_kernel(const float* __restrict__ pcol, int nb16, float n_inv,
                            const float* __restrict__ Wa, float* __restrict__ cvec) {
    int g = blockIdx.x;
    const float4* p4 = (const float4*)(pcol + (size_t)g * nb16 * 16);
    __shared__ float4 sd[TPB];
    __shared__ float cs[16];
    int c4 = threadIdx.x & 3;
    int row = threadIdx.x >> 2;
    float4 acc = make_float4(0.f, 0.f, 0.f, 0.f);
    for (int r = row; r < nb16; r += 64) facc(acc, p4[(size_t)r * 4 + c4]);
    sd[threadIdx.x] = acc;
    __syncthreads();
    if (threadIdx.x < 64) {
        float4 a = sd[threadIdx.x];
        facc(a, sd[threadIdx.x + 64]);
        facc(a, sd[threadIdx.x + 128]);
        facc(a, sd[threadIdx.x + 192]);
        sd[threadIdx.x] = a;
    }
    __syncthreads();
    if (threadIdx.x < 16) {
        float4 a = sd[threadIdx.x];
        facc(a, sd[threadIdx.x + 16]);
        facc(a, sd[threadIdx.x + 32]);
        facc(a, sd[threadIdx.x + 48]);
        sd[threadIdx.x] = a;
    }
    __syncthreads();
    if (threadIdx.x < 4) {
        float4 a = sd[threadIdx.x];
        facc(a, sd[threadIdx.x + 4]);
        facc(a, sd[threadIdx.x + 8]);
        facc(a, sd[threadIdx.x + 12]);
        cs[threadIdx.x * 4 + 0] = a.x * n_inv;
        cs[threadIdx.x * 4 + 1] = a.y * n_inv;
        cs[threadIdx.x * 4 + 2] = a.z * n_inv;
        cs[threadIdx.x * 4 + 3] = a.w * n_inv;
    }
    __syncthreads();
    if (threadIdx.x < 16) {
        float acc2 = 0.f;
#pragma unroll
        for (int i = 0; i < 16; i++) acc2 += cs[i] * Wa[i * 16 + threadIdx.x];
        cvec[g * 16 + threadIdx.x] = tanhf(acc2);
    }
}

// ---------------- attention pooling (per-block partials, no atomics) ----------------

__global__ void pool_kernel(const float* __restrict__ H0, const float* __restrict__ H1, int n,
                            const float* __restrict__ cvec, float* __restrict__ ppool) {
    int g = blockIdx.y;
    const float* H = g ? H1 : H0;
    int c = threadIdx.x & 15;
    float cv = cvec[g * 16 + c];
    int w = (blockIdx.x * blockDim.x + threadIdx.x) / 16;
    int stride = (gridDim.x * blockDim.x) / 16;
    float acc = 0.f;
    for (int node = w; node < n; node += stride) {
        float x = H[(size_t)node * 16 + c];
        float p = x * cv;
        p += __shfl_xor(p, 1, 16);
        p += __shfl_xor(p, 2, 16);
        p += __shfl_xor(p, 4, 16);
        p += __shfl_xor(p, 8, 16);
        float s = 1.f / (1.f + __expf(-p));
        acc += s * x;
    }
    __shared__ float sdata[TPB];
    sdata[threadIdx.x] = acc;
    __syncthreads();
    if (threadIdx.x < 16) {
        float s = 0.f;
        for (int t = threadIdx.x; t < TPB; t += 16) s += sdata[t];
        ppool[((size_t)g * gridDim.x + blockIdx.x) * 16 + threadIdx.x] = s;
    }
}

// ---------------- final: parallel reduce of pool partials + tensor-network scoring ----

__global__ void final_kernel(const float* __restrict__ ppool, int nbp,
                             const float* __restrict__ Wt, const float* __restrict__ Wb,
                             const float* __restrict__ bt, const float* __restrict__ Wfc,
                             const float* __restrict__ bfc, const float* __restrict__ Wsc,
                             const float* __restrict__ bsc, float* __restrict__ out) {
    __shared__ float4 sd4[TPB];
    __shared__ float rep[32], part[TPB], scores[16], tvec[16];
    int t = threadIdx.x;
    {
        const float4* p4 = (const float4*)ppool;
        int g = t >> 7;
        int r0 = (t >> 2) & 31;
        int c4 = t & 3;
        float4 acc = make_float4(0.f, 0.f, 0.f, 0.f);
        for (int r = r0; r < nbp; r += 32)
            facc(acc, p4[((size_t)g * nbp + r) * 4 + c4]);
        sd4[t] = acc;
        __syncthreads();
        for (int st = 16; st >= 1; st >>= 1) {
            if (r0 < st) facc(sd4[t], sd4[t + st * 4]);
            __syncthreads();
        }
        if (r0 == 0) {
            float4 a = sd4[t];
            rep[g * 16 + c4 * 4 + 0] = a.x;
            rep[g * 16 + c4 * 4 + 1] = a.y;
            rep[g * 16 + c4 * 4 + 2] = a.z;
            rep[g * 16 + c4 * 4 + 3] = a.w;
        }
        __syncthreads();
    }
    {
        int p = t >> 4, tt = t & 15;
        float b = 0.f;
#pragma unroll
        for (int q = 0; q < 16; q++)
            b += rep[q] * Wt[(q * 16 + p) * 16 + tt];
        part[t] = b * rep[16 + p];
    }
    __syncthreads();
    if (t < 16) {
        float bil = 0.f;
#pragma unroll
        for (int p = 0; p < 16; p++) bil += part[p * 16 + t];
        float blk = 0.f;
#pragma unroll
        for (int m = 0; m < 16; m++)
            blk += Wb[t * 32 + m] * rep[m] + Wb[t * 32 + 16 + m] * rep[16 + m];
        scores[t] = fmaxf(bil + blk + bt[t], 0.f);
    }
    __syncthreads();
    if (t < 16) {
        float acc = bfc[t];
#pragma unroll
        for (int k = 0; k < 16; k++) acc += scores[k] * Wfc[k * 16 + t];
        tvec[t] = tanhf(acc);
    }
    __syncthreads();
    if (t == 0) {
        float acc = bsc[0];
#pragma unroll
        for (int j = 0; j < 16; j++) acc += tvec[j] * Wsc[j];
        out[0] = 1.f / (1.f + __expf(-acc));
    }
}

// ---------------- launcher ----------------

extern "C" void kernel_launch(void* const* d_in, const int* in_sizes, int n_in,
                              void* d_out, int out_size, void* d_ws, size_t ws_size,
                              hipStream_t stream) {
    const float* X1 = (const float*)d_in[0];
    const float* X2 = (const float*)d_in[1];
    const int* edges1 = (const int*)d_in[2];
    const int* edges2 = (const int*)d_in[3];
    const float* W1 = (const float*)d_in[4];
    const float* b1 = (const float*)d_in[5];
    const float* W2 = (const float*)d_in[6];
    const float* b2 = (const float*)d_in[7];
    const float* W3 = (const float*)d_in[8];
    const float* b3 = (const float*)d_in[9];
    const float* Wa = (const float*)d_in[10];
    const float* Wt = (const float*)d_in[11];
    const float* Wb = (const float*)d_in[12];
    const float* bt = (const float*)d_in[13];
    const float* Wfc = (const float*)d_in[14];
    const float* bfc = (const float*)d_in[15];
    const float* Wsc = (const float*)d_in[16];
    const float* bsc = (const float*)d_in[17];
    float* out = (float*)d_out;

    const int N = in_sizes[0] / 96;
    const int E = in_sizes[2] / 2;
    const int NBUK = (N + BW - 1) / BW;  // buckets (must be <= 1024)
    int cap = ((2 * (E / NBUK)) + 255) & ~255;  // bucket capacity: 2x average, safe
    if (cap < 256) cap = 256;

    char* ws = (char*)d_ws;
    size_t o = 0;
    auto alloc = [&](size_t bytes) {
        void* p = ws + o;
        o += (bytes + 255) & ~(size_t)255;
        return p;
    };
    int* bcur = (int*)alloc((size_t)2 * 1024 * 4);
    int* soff0 = (int*)alloc((size_t)N * 4);
    int* soff1 = (int*)alloc((size_t)N * 4);
    int* eoff0 = (int*)alloc((size_t)N * 4);
    int* eoff1 = (int*)alloc((size_t)N * 4);
    int* col0 = (int*)alloc((size_t)NBUK * cap * 4);
    int* col1 = (int*)alloc((size_t)NBUK * cap * 4);
    int* ebuf0 = (int*)alloc((size_t)NBUK * cap * 4);
    int* ebuf1 = (int*)alloc((size_t)NBUK * cap * 4);
    float* dinv0 = (float*)alloc((size_t)N * 4);
    float* dinv1 = (float*)alloc((size_t)N * 4);
    u16* hwbA0 = (u16*)alloc((size_t)N * 64 * 2);  // layer-1 payload
    u16* hwbA1 = (u16*)alloc((size_t)N * 64 * 2);
    u16* hwbB0 = (u16*)alloc((size_t)N * 32 * 2);  // layer-2 payload
    u16* hwbB1 = (u16*)alloc((size_t)N * 32 * 2);
    u16* hwbC0 = (u16*)alloc((size_t)N * 16 * 2);  // layer-3 payload
    u16* hwbC1 = (u16*)alloc((size_t)N * 16 * 2);
    float* H30 = (float*)alloc((size_t)N * 16 * 4);  // H3 fp32 (pool input)
    float* H31 = (float*)alloc((size_t)N * 16 * 4);

    const int gB2 = (E + 4095) / 4096;
    const int g16 = ((size_t)N * 16 + TPB - 1) / TPB;  // aggs: 16 threads/node
    const int gMM = (N + 63) / 64;
    const int gPool = 256;

    float* pcol = (float*)alloc((size_t)2 * g16 * 16 * 4);
    float* cvecArr = (float*)alloc(32 * 4);
    float* ppool = (float*)alloc((size_t)2 * gPool * 16 * 4);

    hipMemsetAsync(bcur, 0, (size_t)2 * 1024 * 4, stream);

    // capacity-bucket CSR build: scatter -> per-bucket finalize (no count/scan passes)
    bucket_scatter_kernel<<<dim3(gB2, 2), TPB, 0, stream>>>(edges1, edges2, E, bcur,
                                                            ebuf0, ebuf1, NBUK, cap);
    bucket_csr_kernel<<<dim3(NBUK, 2), TPB, 0, stream>>>(ebuf0, ebuf1, bcur, N, cap,
                                                         soff0, soff1, eoff0, eoff1,
                                                         dinv0, dinv1, col0, col1);

    // layer 1 matmul (MFMA 96->64)
    matmul_kernel<96, 64><<<dim3(gMM, 2), TPB, 0, stream>>>(X1, X2, W1, dinv0, dinv1, hwbA0, hwbA1, N);
    // layer-1 agg + fused layer-2 matmul (64 -> H1 -> @W2 -> 32 bf16)
    agg_mm_kernel<64, 32><<<dim3(g16, 2), TPB, 0, stream>>>(
        hwbA0, hwbA1, soff0, soff1, eoff0, eoff1, col0, col1, dinv0, dinv1, b1, W2, hwbB0, hwbB1, N);
    // layer-2 agg + fused layer-3 matmul (32 -> H2 -> @W3 -> 16 bf16)
    agg_mm_kernel<32, 16><<<dim3(g16, 2), TPB, 0, stream>>>(
        hwbB0, hwbB1, soff0, soff1, eoff0, eoff1, col0, col1, dinv0, dinv1, b2, W3, hwbC0, hwbC1, N);
    // layer-3 agg (writes H3 fp32 + colsum partials)
    agg16_kernel<<<dim3(g16, 2), TPB, 0, stream>>>(
        hwbC0, hwbC1, soff0, soff1, eoff0, eoff1, col0, col1, dinv0, dinv1, b3, H30, H31, pcol, N);

    // attention pooling + scoring
    cvec_kernel<<<2, TPB, 0, stream>>>(pcol, g16, 1.0f / (float)N, Wa, cvecArr);
    pool_kernel<<<dim3(gPool, 2), TPB, 0, stream>>>(H30, H31, N, cvecArr, ppool);
    final_kernel<<<1, 256, 0, stream>>>(ppool, gPool, Wt, Wb, bt, Wfc, bfc, Wsc, bsc, out);
}

// Round 3
// 261.049 us; speedup vs baseline: 1.0622x; 1.0622x over previous
//
#include <hip/hip_runtime.h>
#include <hip/hip_bf16.h>

#define TPB 256
#define SH 6
#define BW 64  // nodes per bucket = 1<<SH; NBUK must be <= 1024 (N <= 65536)

typedef unsigned short u16;
typedef __attribute__((ext_vector_type(8))) __bf16 bf16x8;  // MFMA A/B frag (4 VGPRs)
typedef __attribute__((ext_vector_type(4))) float f32x4;    // MFMA C/D frag

// bf16 helpers: payload stored as bf16 (halves gather BW), accumulate in fp32.
__device__ __forceinline__ u16 f_to_bf(float f) {
    unsigned u = __float_as_uint(f);
    return (u16)((u + 0x7fff + ((u >> 16) & 1)) >> 16);  // RNE
}
__device__ __forceinline__ float4 bf4_to_f4(ushort4 v) {
    float4 r;
    r.x = __uint_as_float((unsigned)v.x << 16);
    r.y = __uint_as_float((unsigned)v.y << 16);
    r.z = __uint_as_float((unsigned)v.z << 16);
    r.w = __uint_as_float((unsigned)v.w << 16);
    return r;
}
__device__ __forceinline__ void facc(float4& a, float4 v) {
    a.x += v.x; a.y += v.y; a.z += v.z; a.w += v.w;
}
__device__ __forceinline__ float4 shfl_xor4(float4 v, int mask, int width) {
    v.x = __shfl_xor(v.x, mask, width);
    v.y = __shfl_xor(v.y, mask, width);
    v.z = __shfl_xor(v.z, mask, width);
    v.w = __shfl_xor(v.w, mask, width);
    return v;
}

// XCD-aware block swizzle: MI355X dispatches blockIdx round-robin across 8 XCDs
// (blk&7 = XCD). Map XCDs 0-3 -> graph 0, XCDs 4-7 -> graph 1 so each XCD-half's
// L2 only serves ONE graph's payload working set (6.4MB vs 12.8MB mixed).
__device__ __forceinline__ bool swz_block(int nblk, int& g, int& bx) {
    int blk = blockIdx.x;
    int j = blk & 7;
    g = j >> 2;
    bx = (blk >> 3) * 4 + (j & 3);
    return bx < nblk;
}

// Software-pipelined gather (8B/lane): load 8 indices, issue 8 row-gathers into a
// register array, THEN accumulate (depth-8 MLP; round-1 best config).
template <int C>
__device__ __forceinline__ float4 gather_sum(const u16* __restrict__ HW,
                                             const int* __restrict__ col,
                                             int c0, int ps, int pe) {
    float4 a0 = make_float4(0.f, 0.f, 0.f, 0.f);
    float4 a1 = a0, a2 = a0, a3 = a0;
    int p = ps;
    for (; p + 8 <= pe; p += 8) {
        int j[8];
        ushort4 d[8];
#pragma unroll
        for (int k = 0; k < 8; k++) j[k] = col[p + k];
#pragma unroll
        for (int k = 0; k < 8; k++) d[k] = *(const ushort4*)&HW[(size_t)j[k] * C + c0];
        facc(a0, bf4_to_f4(d[0])); facc(a1, bf4_to_f4(d[1]));
        facc(a2, bf4_to_f4(d[2])); facc(a3, bf4_to_f4(d[3]));
        facc(a0, bf4_to_f4(d[4])); facc(a1, bf4_to_f4(d[5]));
        facc(a2, bf4_to_f4(d[6])); facc(a3, bf4_to_f4(d[7]));
    }
    if (p + 4 <= pe) {
        int j[4];
        ushort4 d[4];
#pragma unroll
        for (int k = 0; k < 4; k++) j[k] = col[p + k];
#pragma unroll
        for (int k = 0; k < 4; k++) d[k] = *(const ushort4*)&HW[(size_t)j[k] * C + c0];
        facc(a0, bf4_to_f4(d[0])); facc(a1, bf4_to_f4(d[1]));
        facc(a2, bf4_to_f4(d[2])); facc(a3, bf4_to_f4(d[3]));
        p += 4;
    }
    for (; p < pe; p++) {
        int j = col[p];
        facc(a0, bf4_to_f4(*(const ushort4*)&HW[(size_t)j * C + c0]));
    }
    facc(a0, a1); facc(a2, a3); facc(a0, a2);
    return a0;
}

// ---------------- capacity-bucket CSR build (no count/scan passes) ----------------
// Bucket b owns region [b*cap, (b+1)*cap) of ebuf/col. bcur is zero-initialized;
// scatter reserves runs per block via one atomicAdd per touched bucket.

__global__ void bucket_scatter_kernel(const int* __restrict__ e0, const int* __restrict__ e1,
                                      int E, int* __restrict__ bcur,
                                      int* __restrict__ ebuf0, int* __restrict__ ebuf1,
                                      int nbuk, int cap) {
    int g = blockIdx.y;
    const int* src = g ? e1 : e0;
    const int* dst = src + E;
    int* ebuf = g ? ebuf1 : ebuf0;
    int* bu = bcur + g * 1024;
    __shared__ int hist[1024];
    for (int t = threadIdx.x; t < 1024; t += TPB) hist[t] = 0;
    __syncthreads();
    int base = blockIdx.x * 4096;
    int pk[16], bk[16], rk[16];
#pragma unroll
    for (int k = 0; k < 16; k++) {
        int e = base + k * TPB + (int)threadIdx.x;
        bk[k] = -1;
        if (e < E) {
            int s = src[e], d = dst[e];
            int b = d >> SH;
            bk[k] = b;
            pk[k] = (s << SH) | (d & (BW - 1));
            rk[k] = atomicAdd(&hist[b], 1);
        }
    }
    __syncthreads();
    for (int t = threadIdx.x; t < nbuk; t += TPB) {
        int h = hist[t];
        hist[t] = h ? atomicAdd(&bu[t], h) : 0;
    }
    __syncthreads();
#pragma unroll
    for (int k = 0; k < 16; k++)
        if (bk[k] >= 0) {
            int pos = hist[bk[k]] + rk[k];
            if (pos < cap) ebuf[(size_t)bk[k] * cap + pos] = pk[k];
        }
}

// Per-bucket: histogram -> local scan -> soff/eoff/dinv -> fill col (bucket-local).
__global__ void bucket_csr_kernel(const int* __restrict__ ebuf0, const int* __restrict__ ebuf1,
                                  const int* __restrict__ bcur, int n, int cap,
                                  int* __restrict__ soff0, int* __restrict__ soff1,
                                  int* __restrict__ eoff0, int* __restrict__ eoff1,
                                  float* __restrict__ dinv0, float* __restrict__ dinv1,
                                  int* __restrict__ col0, int* __restrict__ col1) {
    int g = blockIdx.y;
    int b = blockIdx.x;
    const int* ebuf = g ? ebuf1 : ebuf0;
    int* soff = g ? soff1 : soff0;
    int* eoff = g ? eoff1 : eoff0;
    float* dinv = g ? dinv1 : dinv0;
    int* col = g ? col1 : col0;
    __shared__ int h[BW], nb[BW], nrank[BW];
    int tid = threadIdx.x;
    if (tid < BW) h[tid] = 0;
    __syncthreads();
    int s = b * cap;
    int cnt = min(bcur[g * 1024 + b], cap);
    int e = s + cnt;
    for (int i = s + tid; i < e; i += TPB)
        atomicAdd(&h[ebuf[i] & (BW - 1)], 1);
    __syncthreads();
    if (tid < BW) {
        int v = h[tid];
        int x = v;
        for (int d = 1; d < BW; d <<= 1) {
            int u = __shfl_up(x, d, 64);
            if (tid >= d) x += u;
        }
        int base = s + x - v;  // exclusive prefix within bucket region
        nb[tid] = base;
        nrank[tid] = 0;
        int node = b * BW + tid;
        if (node < n) {
            soff[node] = base;
            eoff[node] = base + v;
            dinv[node] = rsqrtf((float)v + 1.0f);
        }
    }
    __syncthreads();
    for (int i = s + tid; i < e; i += TPB) {
        int p = ebuf[i];
        int lo = p & (BW - 1);
        int r = atomicAdd(&nrank[lo], 1);
        col[nb[lo] + r] = p >> SH;
    }
}

// ---------------- dense matmul via MFMA: Y = bf16( dinv[n] * (X @ W) ) ----------

template <int CIN, int COUT>
__global__ void matmul_kernel(const float* __restrict__ X0, const float* __restrict__ X1,
                              const float* __restrict__ W,
                              const float* __restrict__ dinv0, const float* __restrict__ dinv1,
                              u16* __restrict__ Y0, u16* __restrict__ Y1, int n) {
    constexpr int CINP = CIN + 8;
    constexpr int NT = COUT / 16;
    constexpr int KT = CIN / 32;
    __shared__ u16 Xs[64 * CINP];
    __shared__ u16 Wt[COUT * CINP];

    int g = blockIdx.y;
    const float* X = g ? X1 : X0;
    const float* dinv = g ? dinv1 : dinv0;
    u16* Y = g ? Y1 : Y0;
    int nb0 = blockIdx.x * 64;

    for (int i = threadIdx.x; i < 64 * (CIN / 4); i += TPB) {
        int nn = i / (CIN / 4), kc = i % (CIN / 4);
        float4 v = make_float4(0.f, 0.f, 0.f, 0.f);
        if (nb0 + nn < n) v = *(const float4*)&X[(size_t)(nb0 + nn) * CIN + 4 * kc];
        ushort4 b;
        b.x = f_to_bf(v.x); b.y = f_to_bf(v.y); b.z = f_to_bf(v.z); b.w = f_to_bf(v.w);
        *(ushort4*)&Xs[nn * CINP + 4 * kc] = b;
    }
    for (int i = threadIdx.x; i < CIN * (COUT / 4); i += TPB) {
        int k = i / (COUT / 4), nc4 = i % (COUT / 4);
        float4 v = *(const float4*)&W[(size_t)k * COUT + 4 * nc4];
        Wt[(4 * nc4 + 0) * CINP + k] = f_to_bf(v.x);
        Wt[(4 * nc4 + 1) * CINP + k] = f_to_bf(v.y);
        Wt[(4 * nc4 + 2) * CINP + k] = f_to_bf(v.z);
        Wt[(4 * nc4 + 3) * CINP + k] = f_to_bf(v.w);
    }
    __syncthreads();

    int lane = threadIdx.x & 63;
    int w = threadIdx.x >> 6;
    int m = lane & 15;
    int quad = lane >> 4;

    f32x4 acc[NT];
#pragma unroll
    for (int t = 0; t < NT; t++) acc[t] = (f32x4){0.f, 0.f, 0.f, 0.f};
#pragma unroll
    for (int kt = 0; kt < KT; kt++) {
        int k0 = kt * 32 + quad * 8;
        bf16x8 a = *(const bf16x8*)&Xs[(w * 16 + m) * CINP + k0];
#pragma unroll
        for (int t = 0; t < NT; t++) {
            bf16x8 b = *(const bf16x8*)&Wt[(t * 16 + m) * CINP + k0];
            acc[t] = __builtin_amdgcn_mfma_f32_16x16x32_bf16(a, b, acc[t], 0, 0, 0);
        }
    }
#pragma unroll
    for (int r = 0; r < 4; r++) {
        int node = nb0 + w * 16 + quad * 4 + r;
        if (node < n) {
            float d = dinv[node];
#pragma unroll
            for (int t = 0; t < NT; t++)
                Y[(size_t)node * COUT + t * 16 + m] = f_to_bf(acc[t][r] * d);
        }
    }
}

// ------- fused GCN agg (C channels, bf16 payload) + MFMA next-layer matmul -------
// Block = 16 nodes (TPN=16 threads/node). Gather+relu produces bf16 H rows in LDS;
// then waves 0..COUT2/16-1 compute Y = bf16(dinv * (H @ W2)) with 16x16x32 MFMA
// (replaces the scalar epilogue: ~80 ds_read + 128 FMA per THREAD -> 2-4 MFMA
// per block). W2 is staged transposed as bf16 in LDS.

template <int C, int SPLIT, int COUT2>
__global__ __launch_bounds__(TPB, 2)
void agg_mm_kernel(const u16* __restrict__ HW0, const u16* __restrict__ HW1,
                   const int* __restrict__ soff0, const int* __restrict__ soff1,
                   const int* __restrict__ eoff0, const int* __restrict__ eoff1,
                   const int* __restrict__ col0, const int* __restrict__ col1,
                   const float* __restrict__ dinv0, const float* __restrict__ dinv1,
                   const float* __restrict__ bias, const float* __restrict__ W2,
                   u16* __restrict__ Y0, u16* __restrict__ Y1, int n, int nblk) {
    constexpr int CH = C / 4;        // lanes covering one row (4 ch / 8B each)
    constexpr int TPN = CH * SPLIT;  // 16
    constexpr int CP = C + 8;        // padded LDS row stride (u16); keeps 16B align
    constexpr int NT2 = COUT2 / 16;  // MFMA col-tiles (waves used in epilogue)
    constexpr int KT2 = C / 32;      // MFMA k-tiles
    __shared__ __align__(16) u16 HsB[16 * CP];
    __shared__ __align__(16) u16 WtB[COUT2 * CP];

    int g, bx;
    if (!swz_block(nblk, g, bx)) return;
    const u16* HW = g ? HW1 : HW0;
    const int* soff = g ? soff1 : soff0;
    const int* eoff = g ? eoff1 : eoff0;
    const int* col = g ? col1 : col0;
    const float* dinv = g ? dinv1 : dinv0;
    u16* Y = g ? Y1 : Y0;

    // stage W2 transposed (bf16) while gather loads are in flight
    for (int idx = threadIdx.x; idx < C * COUT2; idx += TPB) {
        int k = idx / COUT2, nc = idx % COUT2;
        WtB[nc * CP + k] = f_to_bf(W2[idx]);
    }

    int tid = bx * TPB + (int)threadIdx.x;
    int node = tid / TPN;
    int nl = threadIdx.x / TPN;
    int part = threadIdx.x % TPN;
    int sp = part / CH;
    int c0 = (part % CH) * 4;
    float4 o = make_float4(0.f, 0.f, 0.f, 0.f);
    if (node < n) {
        int s = soff[node], e = eoff[node];
        int len = e - s;
        int chunk = (len + SPLIT - 1) / SPLIT;
        int ps = s + sp * chunk;
        int pe = min(ps + chunk, e);
        float4 r = gather_sum<C>(HW, col, c0, ps, pe);
#pragma unroll
        for (int m = CH; m < TPN; m <<= 1) facc(r, shfl_xor4(r, m, TPN));
        if (sp == 0) {
            float di = dinv[node];
            float4 self = bf4_to_f4(*(const ushort4*)&HW[(size_t)node * C + c0]);
            float4 b4 = *(const float4*)&bias[c0];
            o.x = fmaxf(di * (r.x + self.x) + b4.x, 0.f);
            o.y = fmaxf(di * (r.y + self.y) + b4.y, 0.f);
            o.z = fmaxf(di * (r.z + self.z) + b4.z, 0.f);
            o.w = fmaxf(di * (r.w + self.w) + b4.w, 0.f);
        }
    }
    if (sp == 0) {  // zeros for tail nodes
        ushort4 hb;
        hb.x = f_to_bf(o.x); hb.y = f_to_bf(o.y); hb.z = f_to_bf(o.z); hb.w = f_to_bf(o.w);
        *(ushort4*)&HsB[nl * CP + c0] = hb;
    }
    __syncthreads();

    // MFMA epilogue: wave w computes 16 nodes x out-cols [w*16, w*16+16)
    int lane = threadIdx.x & 63;
    int w = threadIdx.x >> 6;
    if (w < NT2) {
        int m = lane & 15;
        int quad = lane >> 4;
        f32x4 acc = (f32x4){0.f, 0.f, 0.f, 0.f};
#pragma unroll
        for (int kt = 0; kt < KT2; kt++) {
            int k0 = kt * 32 + quad * 8;
            bf16x8 a = *(const bf16x8*)&HsB[m * CP + k0];
            bf16x8 b = *(const bf16x8*)&WtB[(w * 16 + m) * CP + k0];
            acc = __builtin_amdgcn_mfma_f32_16x16x32_bf16(a, b, acc, 0, 0, 0);
        }
        int base16 = bx * 16;
#pragma unroll
        for (int r = 0; r < 4; r++) {
            int onode = base16 + quad * 4 + r;
            if (onode < n)
                Y[(size_t)onode * COUT2 + w * 16 + m] = f_to_bf(acc[r] * dinv[onode]);
        }
    }
}

// Layer-3 aggregation (C=16, SPLIT=4) + per-block colsum partials (NO atomics).
__global__ __launch_bounds__(TPB, 2)
void agg16_kernel(const u16* __restrict__ HW0, const u16* __restrict__ HW1,
                  const int* __restrict__ soff0, const int* __restrict__ soff1,
                  const int* __restrict__ eoff0, const int* __restrict__ eoff1,
                  const int* __restrict__ col0, const int* __restrict__ col1,
                  const float* __restrict__ dinv0, const float* __restrict__ dinv1,
                  const float* __restrict__ bias,
                  float* __restrict__ out0, float* __restrict__ out1,
                  float* __restrict__ pcol, int n, int nblk) {
    int g, bx;
    if (!swz_block(nblk, g, bx)) return;
    const u16* HW = g ? HW1 : HW0;
    const int* soff = g ? soff1 : soff0;
    const int* eoff = g ? eoff1 : eoff0;
    const int* col = g ? col1 : col0;
    const float* dinv = g ? dinv1 : dinv0;
    float* outp = g ? out1 : out0;
    int tid = bx * TPB + (int)threadIdx.x;
    int node = tid / 16;
    int part = tid % 16;
    int sp = part / 4;
    int c0 = (part % 4) * 4;
    float4 o = make_float4(0.f, 0.f, 0.f, 0.f);
    if (node < n) {
        int s = soff[node], e = eoff[node];
        int len = e - s;
        int chunk = (len + 3) / 4;
        int ps = s + sp * chunk;
        int pe = min(ps + chunk, e);
        float4 r = gather_sum<16>(HW, col, c0, ps, pe);
        facc(r, shfl_xor4(r, 4, 16));
        facc(r, shfl_xor4(r, 8, 16));
        if (sp == 0) {
            float di = dinv[node];
            float4 self = bf4_to_f4(*(const ushort4*)&HW[(size_t)node * 16 + c0]);
            float4 b4 = *(const float4*)&bias[c0];
            o.x = di * (r.x + self.x) + b4.x;
            o.y = di * (r.y + self.y) + b4.y;
            o.z = di * (r.z + self.z) + b4.z;
            o.w = di * (r.w + self.w) + b4.w;
            *(float4*)&outp[(size_t)node * 16 + c0] = o;
        }
    }
    // per-block colsum partial (only sp==0 lanes hold data)
    __shared__ float4 sd[TPB];
    sd[threadIdx.x] = (node < n && sp == 0) ? o : make_float4(0.f, 0.f, 0.f, 0.f);
    __syncthreads();
    if (threadIdx.x < 64) {
        float4 a = sd[threadIdx.x];
        facc(a, sd[threadIdx.x + 64]);
        facc(a, sd[threadIdx.x + 128]);
        facc(a, sd[threadIdx.x + 192]);
        sd[threadIdx.x] = a;
    }
    __syncthreads();
    if (threadIdx.x < 16) {
        float4 a = sd[threadIdx.x];
        facc(a, sd[threadIdx.x + 16]);
        facc(a, sd[threadIdx.x + 32]);
        facc(a, sd[threadIdx.x + 48]);
        sd[threadIdx.x] = a;
    }
    __syncthreads();
    if (threadIdx.x < 4)
        *(float4*)&pcol[((size_t)g * nblk + bx) * 16 + threadIdx.x * 4] = sd[threadIdx.x];
}

// ---------------- cvec: coalesced reduce of pcol partials + tanh(mean @ Wa) ----------

__global__ void cvec_kernel(const float* __restrict__ pcol, int nb16, float n_inv,
                            const float* __restrict__ Wa, float* __restrict__ cvec) {
    int g = blockIdx.x;
    const float4* p4 = (const float4*)(pcol + (size_t)g * nb16 * 16);
    __shared__ float4 sd[TPB];
    __shared__ float cs[16];
    int c4 = threadIdx.x & 3;
    int row = threadIdx.x >> 2;
    float4 acc = make_float4(0.f, 0.f, 0.f, 0.f);
    for (int r = row; r < nb16; r += 64) facc(acc, p4[(size_t)r * 4 + c4]);
    sd[threadIdx.x] = acc;
    __syncthreads();
    if (threadIdx.x < 64) {
        float4 a = sd[threadIdx.x];
        facc(a, sd[threadIdx.x + 64]);
        facc(a, sd[threadIdx.x + 128]);
        facc(a, sd[threadIdx.x + 192]);
        sd[threadIdx.x] = a;
    }
    __syncthreads();
    if (threadIdx.x < 16) {
        float4 a = sd[threadIdx.x];
        facc(a, sd[threadIdx.x + 16]);
        facc(a, sd[threadIdx.x + 32]);
        facc(a, sd[threadIdx.x + 48]);
        sd[threadIdx.x] = a;
    }
    __syncthreads();
    if (threadIdx.x < 4) {
        float4 a = sd[threadIdx.x];
        facc(a, sd[threadIdx.x + 4]);
        facc(a, sd[threadIdx.x + 8]);
        facc(a, sd[threadIdx.x + 12]);
        cs[threadIdx.x * 4 + 0] = a.x * n_inv;
        cs[threadIdx.x * 4 + 1] = a.y * n_inv;
        cs[threadIdx.x * 4 + 2] = a.z * n_inv;
        cs[threadIdx.x * 4 + 3] = a.w * n_inv;
    }
    __syncthreads();
    if (threadIdx.x < 16) {
        float acc2 = 0.f;
#pragma unroll
        for (int i = 0; i < 16; i++) acc2 += cs[i] * Wa[i * 16 + threadIdx.x];
        cvec[g * 16 + threadIdx.x] = tanhf(acc2);
    }
}

// ---------------- attention pooling (per-block partials, no atomics) ----------------

__global__ void pool_kernel(const float* __restrict__ H0, const float* __restrict__ H1, int n,
                            const float* __restrict__ cvec, float* __restrict__ ppool) {
    int g = blockIdx.y;
    const float* H = g ? H1 : H0;
    int c = threadIdx.x & 15;
    float cv = cvec[g * 16 + c];
    int w = (blockIdx.x * blockDim.x + threadIdx.x) / 16;
    int stride = (gridDim.x * blockDim.x) / 16;
    float acc = 0.f;
    for (int node = w; node < n; node += stride) {
        float x = H[(size_t)node * 16 + c];
        float p = x * cv;
        p += __shfl_xor(p, 1, 16);
        p += __shfl_xor(p, 2, 16);
        p += __shfl_xor(p, 4, 16);
        p += __shfl_xor(p, 8, 16);
        float s = 1.f / (1.f + __expf(-p));
        acc += s * x;
    }
    __shared__ float sdata[TPB];
    sdata[threadIdx.x] = acc;
    __syncthreads();
    if (threadIdx.x < 16) {
        float s = 0.f;
        for (int t = threadIdx.x; t < TPB; t += 16) s += sdata[t];
        ppool[((size_t)g * gridDim.x + blockIdx.x) * 16 + threadIdx.x] = s;
    }
}

// ---------------- final: parallel reduce of pool partials + tensor-network scoring ----

__global__ void final_kernel(const float* __restrict__ ppool, int nbp,
                             const float* __restrict__ Wt, const float* __restrict__ Wb,
                             const float* __restrict__ bt, const float* __restrict__ Wfc,
                             const float* __restrict__ bfc, const float* __restrict__ Wsc,
                             const float* __restrict__ bsc, float* __restrict__ out) {
    __shared__ float4 sd4[TPB];
    __shared__ float rep[32], part[TPB], scores[16], tvec[16];
    int t = threadIdx.x;
    {
        const float4* p4 = (const float4*)ppool;
        int g = t >> 7;
        int r0 = (t >> 2) & 31;
        int c4 = t & 3;
        float4 acc = make_float4(0.f, 0.f, 0.f, 0.f);
        for (int r = r0; r < nbp; r += 32)
            facc(acc, p4[((size_t)g * nbp + r) * 4 + c4]);
        sd4[t] = acc;
        __syncthreads();
        for (int st = 16; st >= 1; st >>= 1) {
            if (r0 < st) facc(sd4[t], sd4[t + st * 4]);
            __syncthreads();
        }
        if (r0 == 0) {
            float4 a = sd4[t];
            rep[g * 16 + c4 * 4 + 0] = a.x;
            rep[g * 16 + c4 * 4 + 1] = a.y;
            rep[g * 16 + c4 * 4 + 2] = a.z;
            rep[g * 16 + c4 * 4 + 3] = a.w;
        }
        __syncthreads();
    }
    {
        int p = t >> 4, tt = t & 15;
        float b = 0.f;
#pragma unroll
        for (int q = 0; q < 16; q++)
            b += rep[q] * Wt[(q * 16 + p) * 16 + tt];
        part[t] = b * rep[16 + p];
    }
    __syncthreads();
    if (t < 16) {
        float bil = 0.f;
#pragma unroll
        for (int p = 0; p < 16; p++) bil += part[p * 16 + t];
        float blk = 0.f;
#pragma unroll
        for (int m = 0; m < 16; m++)
            blk += Wb[t * 32 + m] * rep[m] + Wb[t * 32 + 16 + m] * rep[16 + m];
        scores[t] = fmaxf(bil + blk + bt[t], 0.f);
    }
    __syncthreads();
    if (t < 16) {
        float acc = bfc[t];
#pragma unroll
        for (int k = 0; k < 16; k++) acc += scores[k] * Wfc[k * 16 + t];
        tvec[t] = tanhf(acc);
    }
    __syncthreads();
    if (t == 0) {
        float acc = bsc[0];
#pragma unroll
        for (int j = 0; j < 16; j++) acc += tvec[j] * Wsc[j];
        out[0] = 1.f / (1.f + __expf(-acc));
    }
}

// ---------------- launcher ----------------

extern "C" void kernel_launch(void* const* d_in, const int* in_sizes, int n_in,
                              void* d_out, int out_size, void* d_ws, size_t ws_size,
                              hipStream_t stream) {
    const float* X1 = (const float*)d_in[0];
    const float* X2 = (const float*)d_in[1];
    const int* edges1 = (const int*)d_in[2];
    const int* edges2 = (const int*)d_in[3];
    const float* W1 = (const float*)d_in[4];
    const float* b1 = (const float*)d_in[5];
    const float* W2 = (const float*)d_in[6];
    const float* b2 = (const float*)d_in[7];
    const float* W3 = (const float*)d_in[8];
    const float* b3 = (const float*)d_in[9];
    const float* Wa = (const float*)d_in[10];
    const float* Wt = (const float*)d_in[11];
    const float* Wb = (const float*)d_in[12];
    const float* bt = (const float*)d_in[13];
    const float* Wfc = (const float*)d_in[14];
    const float* bfc = (const float*)d_in[15];
    const float* Wsc = (const float*)d_in[16];
    const float* bsc = (const float*)d_in[17];
    float* out = (float*)d_out;

    const int N = in_sizes[0] / 96;
    const int E = in_sizes[2] / 2;
    const int NBUK = (N + BW - 1) / BW;  // buckets (must be <= 1024)
    int cap = ((2 * (E / NBUK)) + 255) & ~255;  // bucket capacity: 2x average, safe
    if (cap < 256) cap = 256;

    char* ws = (char*)d_ws;
    size_t o = 0;
    auto alloc = [&](size_t bytes) {
        void* p = ws + o;
        o += (bytes + 255) & ~(size_t)255;
        return p;
    };
    int* bcur = (int*)alloc((size_t)2 * 1024 * 4);
    int* soff0 = (int*)alloc((size_t)N * 4);
    int* soff1 = (int*)alloc((size_t)N * 4);
    int* eoff0 = (int*)alloc((size_t)N * 4);
    int* eoff1 = (int*)alloc((size_t)N * 4);
    int* col0 = (int*)alloc((size_t)NBUK * cap * 4);
    int* col1 = (int*)alloc((size_t)NBUK * cap * 4);
    int* ebuf0 = (int*)alloc((size_t)NBUK * cap * 4);
    int* ebuf1 = (int*)alloc((size_t)NBUK * cap * 4);
    float* dinv0 = (float*)alloc((size_t)N * 4);
    float* dinv1 = (float*)alloc((size_t)N * 4);
    u16* hwbA0 = (u16*)alloc((size_t)N * 64 * 2);  // layer-1 payload
    u16* hwbA1 = (u16*)alloc((size_t)N * 64 * 2);
    u16* hwbB0 = (u16*)alloc((size_t)N * 32 * 2);  // layer-2 payload
    u16* hwbB1 = (u16*)alloc((size_t)N * 32 * 2);
    u16* hwbC0 = (u16*)alloc((size_t)N * 16 * 2);  // layer-3 payload
    u16* hwbC1 = (u16*)alloc((size_t)N * 16 * 2);
    float* H30 = (float*)alloc((size_t)N * 16 * 4);  // H3 fp32 (pool input)
    float* H31 = (float*)alloc((size_t)N * 16 * 4);

    const int gB2 = (E + 4095) / 4096;
    const int g16 = ((size_t)N * 16 + TPB - 1) / TPB;  // aggs: 16 threads/node
    const int gSwz = 8 * ((g16 + 3) / 4);              // XCD-swizzled 1D grid
    const int gMM = (N + 63) / 64;
    const int gPool = 256;

    float* pcol = (float*)alloc((size_t)2 * g16 * 16 * 4);
    float* cvecArr = (float*)alloc(32 * 4);
    float* ppool = (float*)alloc((size_t)2 * gPool * 16 * 4);

    hipMemsetAsync(bcur, 0, (size_t)2 * 1024 * 4, stream);

    // capacity-bucket CSR build: scatter -> per-bucket finalize (no count/scan passes)
    bucket_scatter_kernel<<<dim3(gB2, 2), TPB, 0, stream>>>(edges1, edges2, E, bcur,
                                                            ebuf0, ebuf1, NBUK, cap);
    bucket_csr_kernel<<<dim3(NBUK, 2), TPB, 0, stream>>>(ebuf0, ebuf1, bcur, N, cap,
                                                         soff0, soff1, eoff0, eoff1,
                                                         dinv0, dinv1, col0, col1);

    // layer 1 matmul (MFMA 96->64)
    matmul_kernel<96, 64><<<dim3(gMM, 2), TPB, 0, stream>>>(X1, X2, W1, dinv0, dinv1, hwbA0, hwbA1, N);
    // layer-1 agg + fused layer-2 MFMA matmul (64 -> H1 -> @W2 -> 32 bf16)
    agg_mm_kernel<64, 1, 32><<<gSwz, TPB, 0, stream>>>(
        hwbA0, hwbA1, soff0, soff1, eoff0, eoff1, col0, col1, dinv0, dinv1, b1, W2,
        hwbB0, hwbB1, N, g16);
    // layer-2 agg + fused layer-3 MFMA matmul (32 -> H2 -> @W3 -> 16 bf16)
    agg_mm_kernel<32, 2, 16><<<gSwz, TPB, 0, stream>>>(
        hwbB0, hwbB1, soff0, soff1, eoff0, eoff1, col0, col1, dinv0, dinv1, b2, W3,
        hwbC0, hwbC1, N, g16);
    // layer-3 agg (writes H3 fp32 + colsum partials)
    agg16_kernel<<<gSwz, TPB, 0, stream>>>(
        hwbC0, hwbC1, soff0, soff1, eoff0, eoff1, col0, col1, dinv0, dinv1, b3,
        H30, H31, pcol, N, g16);

    // attention pooling + scoring
    cvec_kernel<<<2, TPB, 0, stream>>>(pcol, g16, 1.0f / (float)N, Wa, cvecArr);
    pool_kernel<<<dim3(gPool, 2), TPB, 0, stream>>>(H30, H31, N, cvecArr, ppool);
    final_kernel<<<1, 256, 0, stream>>>(ppool, gPool, Wt, Wb, bt, Wfc, bfc, Wsc, bsc, out);
}